// Round 22
// baseline (537.098 us; speedup 1.0000x reference)
//
#include <hip/hip_runtime.h>

// Swin block. fp32 I/O, bf16 internal MFMA operands, bf16 trunk.
// R22: proj/fc2 tile widened to BM=128 x BN=128 (BK=64): 2x MFMA work per
//      barrier interval vs BN=64 (latency cover), B amortized over 2x output.
//      STAGE generalized (BI sub-loads for B); vmcnt = prev-stage load count.

using bf16x8 = __attribute__((ext_vector_type(8))) short;
using f32x4  = __attribute__((ext_vector_type(4))) float;
using h16x4  = __attribute__((ext_vector_type(4))) _Float16;

#define CDIM  384
#define N3C   1152
#define NHID  1536

__device__ __forceinline__ float bf2f(unsigned short u){
  union { unsigned int i; float f; } x; x.i = ((unsigned int)u) << 16; return x.f;
}
__device__ __forceinline__ unsigned short f2bf(float f){
  union { float f; unsigned int i; } x; x.f = f;
  unsigned int r = x.i + 0x7fffu + ((x.i >> 16) & 1u);   // RNE
  return (unsigned short)(r >> 16);
}
__device__ __forceinline__ void gload16(const void* g, void* l){
  __builtin_amdgcn_global_load_lds(
      (const __attribute__((address_space(1))) unsigned int*)g,
      (__attribute__((address_space(3))) unsigned int*)l, 16, 0, 0);
}

// ---------------- transpose-convert: wt[n*K+k] = bf16(w[k*N+n]) ----------------
__global__ __launch_bounds__(256)
void cvtT_kern(const float* __restrict__ w, unsigned short* __restrict__ wt, int K, int N){
  __shared__ unsigned short t[32][33];
  int bk = blockIdx.x, bn = blockIdx.y;
  int tr = threadIdx.x >> 5, tc = threadIdx.x & 31;
  #pragma unroll
  for (int r = tr; r < 32; r += 8)
    t[r][tc] = f2bf(w[(size_t)(bk*32 + r) * N + bn*32 + tc]);
  __syncthreads();
  #pragma unroll
  for (int r = tr; r < 32; r += 8)
    wt[(size_t)(bn*32 + r) * K + bk*32 + tc] = t[tc][r];
}

// ---------------- dw weights: [1536][9] fp32 -> [9][1536] f16 ----------------
__global__ __launch_bounds__(256)
void cvtDW_kern(const float* __restrict__ k, unsigned short* __restrict__ wt){
  int i = blockIdx.x * 256 + threadIdx.x;
  if (i < NHID * 9){
    int c = i / 9, tap = i % 9;
    union { _Float16 h; unsigned short u; } cvt; cvt.h = (_Float16)k[i];
    wt[tap * NHID + c] = cvt.u;
  }
}

// ---------------- LayerNorm fp32-in (+optional roll+window gather), bf16 out ----------
__global__ __launch_bounds__(64)
void ln_kern(const float* __restrict__ xin, const float* __restrict__ g,
             const float* __restrict__ bsh, unsigned short* __restrict__ out,
             int row_off, int do_shift)
{
  int blk = blockIdx.x, t = threadIdx.x;
  size_t src;
  if (do_shift){
    int gl = row_off + blk;
    int bb = gl / 3136, rem = gl % 3136;
    int wi = rem / 49, l = rem % 49;
    int h = (wi >> 3) * 7 + l / 7;
    int w = (wi & 7) * 7 + l % 7;
    int sh = h + 3; if (sh >= 56) sh -= 56;    // roll(-3)
    int sw = w + 3; if (sw >= 56) sw -= 56;
    src = ((size_t)bb * 3136 + sh * 56 + sw) * CDIM;
  } else {
    src = (size_t)blk * CDIM;
  }
  float v[6]; float s = 0.f;
  #pragma unroll
  for (int j = 0; j < 6; j++){ v[j] = xin[src + j*64 + t]; s += v[j]; }
  #pragma unroll
  for (int m = 32; m >= 1; m >>= 1) s += __shfl_xor(s, m);
  float mean = s * (1.f/384.f);
  float q = 0.f;
  #pragma unroll
  for (int j = 0; j < 6; j++){ float d = v[j] - mean; q += d * d; }
  #pragma unroll
  for (int m = 32; m >= 1; m >>= 1) q += __shfl_xor(q, m);
  float rstd = rsqrtf(q * (1.f/384.f) + 1e-5f);
  size_t dst = (size_t)blk * CDIM;
  #pragma unroll
  for (int j = 0; j < 6; j++){
    int c = j*64 + t;
    out[dst + c] = f2bf((v[j] - mean) * rstd * g[c] + bsh[c]);
  }
}

// ---------------- LayerNorm bf16-in (linear), bf16 out ----------
__global__ __launch_bounds__(64)
void lnb_kern(const unsigned short* __restrict__ xin, const float* __restrict__ g,
              const float* __restrict__ bsh, unsigned short* __restrict__ out)
{
  int blk = blockIdx.x, t = threadIdx.x;
  size_t src = (size_t)blk * CDIM;
  float v[6]; float s = 0.f;
  #pragma unroll
  for (int j = 0; j < 6; j++){ v[j] = bf2f(xin[src + j*64 + t]); s += v[j]; }
  #pragma unroll
  for (int m = 32; m >= 1; m >>= 1) s += __shfl_xor(s, m);
  float mean = s * (1.f/384.f);
  float q = 0.f;
  #pragma unroll
  for (int j = 0; j < 6; j++){ float d = v[j] - mean; q += d * d; }
  #pragma unroll
  for (int m = 32; m >= 1; m >>= 1) q += __shfl_xor(q, m);
  float rstd = rsqrtf(q * (1.f/384.f) + 1e-5f);
  #pragma unroll
  for (int j = 0; j < 6; j++){
    int c = j*64 + t;
    out[src + c] = f2bf((v[j] - mean) * rstd * g[c] + bsh[c]);
  }
}

// ---------------- MFMA GEMM, 2-phase dbuf (R18 form), XCD-chunked 1-D grid ----------------
// MODE 0: plain bf16 out (qkv). 1: +bias, f16 out (fc1). 2: proj->fp32 trunk (split path).
// 3: fc2 fp32-resid (split path). 5: fc2 bf16-resid -> fp32 out. 6: proj -> bf16 x2b.
template<int MODE, int BM, int BN, int BK>
__global__ __launch_bounds__(BM*2)
void gemm_kern(const unsigned short* __restrict__ A, int lda,
               const unsigned short* __restrict__ Bt, int K, int N,
               const float* __restrict__ bias, const float* __restrict__ resid,
               void* __restrict__ outv, int row_off)
{
  constexpr int NI = BN / 32;
  constexpr int T  = BM * 2;
  constexpr int SUBK = BK / 32;
  constexpr int BI = (BN * 32) / (T * 8);       // B sub-loads per K=32 slice (>=1)
  constexpr int LOADS = SUBK * (2 + BI);        // gloads per STAGE
  __shared__ __align__(16) unsigned short Al[2][SUBK * BM * 32];
  __shared__ __align__(16) unsigned short Bl[2][SUBK * BN * 32];
  int tid = threadIdx.x;
  int lane = tid & 63, wv = tid >> 6;

  // bijective XCD chunk remap (m204)
  int nwg = gridDim.x, bid = blockIdx.x;
  int q8 = nwg >> 3, r8 = nwg & 7;
  int xcd = bid & 7, idx = bid >> 3;
  int l = ((xcd < r8) ? xcd * (q8 + 1) : r8 * (q8 + 1) + (xcd - r8) * q8) + idx;
  const int NT = N / BN;
  int m0 = (l / NT) * BM, n0 = (l % NT) * BN;

  const int wrow = (wv >> 1) * 64;
  const int wcol = (wv & 1) * (BN / 2);
  const int lr = lane & 15, lk = (lane >> 4) * 8;

  auto STAGE = [&](int buf, int k0){
    #pragma unroll
    for (int s = 0; s < SUBK; s++){
      #pragma unroll
      for (int i = 0; i < 2; i++){
        int c = i*T + tid;
        gload16(&A[(size_t)(m0 + (c >> 2)) * lda + k0 + s*32 + (c & 3) * 8],
                &Al[buf][s*BM*32 + (i*T + wv*64) * 8]);
      }
      #pragma unroll
      for (int i = 0; i < BI; i++){
        int c = i*T + tid;
        gload16(&Bt[(size_t)(n0 + (c >> 2)) * K + k0 + s*32 + (c & 3) * 8],
                &Bl[buf][s*BN*32 + (i*T + wv*64) * 8]);
      }
    }
  };

  f32x4 acc[4][NI] = {};
  const int nt = K / BK;
  STAGE(0, 0);
  for (int t = 0; t < nt; ++t){
    int cur = t & 1;
    if (t + 1 < nt){
      STAGE(cur ^ 1, (t + 1) * BK);
      if constexpr (LOADS == 3)      asm volatile("s_waitcnt vmcnt(3)" ::: "memory");
      else if constexpr (LOADS == 4) asm volatile("s_waitcnt vmcnt(4)" ::: "memory");
      else if constexpr (LOADS == 6) asm volatile("s_waitcnt vmcnt(6)" ::: "memory");
      else if constexpr (LOADS == 8) asm volatile("s_waitcnt vmcnt(8)" ::: "memory");
      else                           asm volatile("s_waitcnt vmcnt(0)" ::: "memory");
    } else {
      asm volatile("s_waitcnt vmcnt(0)" ::: "memory");
    }
    __builtin_amdgcn_s_barrier();
    __builtin_amdgcn_sched_barrier(0);
    #pragma unroll
    for (int kk = 0; kk < SUBK; kk++){
      bf16x8 af[4], bfr[NI];
      #pragma unroll
      for (int mi = 0; mi < 4; mi++)
        af[mi] = *(const bf16x8*)&Al[cur][kk*BM*32 + (wrow + mi*16 + lr)*32 + lk];
      #pragma unroll
      for (int ni = 0; ni < NI; ni++)
        bfr[ni] = *(const bf16x8*)&Bl[cur][kk*BN*32 + (wcol + ni*16 + lr)*32 + lk];
      #pragma unroll
      for (int mi = 0; mi < 4; mi++)
        #pragma unroll
        for (int ni = 0; ni < NI; ni++)
          acc[mi][ni] = __builtin_amdgcn_mfma_f32_16x16x32_bf16(af[mi], bfr[ni], acc[mi][ni], 0, 0, 0);
    }
    __builtin_amdgcn_sched_barrier(0);
    __builtin_amdgcn_s_barrier();
    __builtin_amdgcn_sched_barrier(0);
  }

  #pragma unroll
  for (int mi = 0; mi < 4; mi++)
  #pragma unroll
  for (int ni = 0; ni < NI; ni++)
  #pragma unroll
  for (int j = 0; j < 4; j++){
    int row = m0 + wrow + mi*16 + (lane >> 4) * 4 + j;   // C/D layout (m89/m91)
    int col = n0 + wcol + ni*16 + lr;
    float val = acc[mi][ni][j];
    if (MODE == 0){
      ((unsigned short*)outv)[(size_t)row * N + col] = f2bf(val);
    } else if (MODE == 1){
      union { _Float16 h; unsigned short u; } cvt;
      cvt.h = (_Float16)(val + bias[col]);
      ((unsigned short*)outv)[(size_t)row * N + col] = cvt.u;
    } else if (MODE == 2 || MODE == 6){
      val += bias[col];
      int gl = row_off + row;
      int bb = gl / 3136, rem = gl % 3136;
      int wi = rem / 49, l2 = rem % 49;
      int n = ((wi >> 3) * 7 + l2 / 7) * 56 + (wi & 7) * 7 + l2 % 7;  // window reverse
      size_t idx2 = ((size_t)bb * 3136 + n) * CDIM + col;
      if (MODE == 2) ((float*)outv)[idx2] = resid[idx2] + val;
      else           ((unsigned short*)outv)[idx2] = f2bf(resid[idx2] + val);
    } else if (MODE == 5){
      size_t idx2 = (size_t)(row_off + row) * CDIM + col;
      float r = bf2f(((const unsigned short*)resid)[idx2]);
      ((float*)outv)[idx2] = r + val + bias[col];
    } else {
      size_t idx2 = (size_t)(row_off + row) * CDIM + col;
      ((float*)outv)[idx2] = resid[idx2] + val + bias[col];
    }
  }
}

// ---------------- Windowed attention: 4 waves per (window, head), one q-tile per wave ------
__global__ __launch_bounds__(256)
void attn_kern(unsigned short* __restrict__ qkv)
{
  __shared__ __align__(16) unsigned short Vt[32 * 64];
  __shared__ __align__(16) unsigned short Pl[4][16 * 64];
  __shared__ unsigned char idt[49];
  int blk = blockIdx.x;
  int win = blk / 12, head = blk % 12;
  int tid = threadIdx.x;
  int wid = tid >> 6, l = tid & 63;
  int g = l >> 4, q15 = l & 15;
  size_t base = (size_t)win * 49 * N3C + (size_t)head * 32;
  const unsigned short* kp = qkv + base + 384;
  const unsigned short* vp = qkv + base + 768;

  int wi = win & 63;
  if (wid == 0 && l < 49){
    int h = (wi >> 3) * 7 + l / 7;
    int w = (wi & 7) * 7 + l % 7;
    idt[l] = (unsigned char)((h < 49 ? 0 : (h < 53 ? 1 : 2)) * 3 +
                             (w < 49 ? 0 : (w < 53 ? 1 : 2)));
  }
  {
    int c = tid;
    int key = c >> 2, keyc = min(key, 48), d0 = (c & 3) * 8;
    bf16x8 v = *(const bf16x8*)&vp[(size_t)keyc * N3C + d0];
    #pragma unroll
    for (int j = 0; j < 8; j++){
      int d = d0 + j;
      *(unsigned short*)((char*)Vt + d * 128 + ((key * 2) ^ ((d & 7) << 4))) =
          (unsigned short)v[j];
    }
  }
  __syncthreads();

  bf16x8 kf[4];
  #pragma unroll
  for (int kt = 0; kt < 4; kt++){
    int krow = min(kt * 16 + q15, 48);
    kf[kt] = *(const bf16x8*)&kp[(size_t)krow * N3C + g * 8];
  }
  bf16x8 vf[2][2];
  #pragma unroll
  for (int kb = 0; kb < 2; kb++)
    #pragma unroll
    for (int nt = 0; nt < 2; nt++){
      int n = nt * 16 + q15;
      vf[kb][nt] = *(const bf16x8*)((char*)Vt + n * 128 + ((kb * 64 + g * 16) ^ ((n & 7) << 4)));
    }
  unsigned int kidp[4];
  #pragma unroll
  for (int kt = 0; kt < 4; kt++){
    unsigned int p = 0;
    #pragma unroll
    for (int r = 0; r < 4; r++)
      p |= ((unsigned int)idt[min(kt * 16 + 4 * g + r, 48)]) << (8 * r);
    kidp[kt] = p;
  }

  const float scale = 0.17677669529663687f;
  const f32x4 zf = {0.f, 0.f, 0.f, 0.f};
  const int qt = wid;
  int qrow = min(qt * 16 + q15, 48);
  bf16x8 qf = *(const bf16x8*)&qkv[base + (size_t)qrow * N3C + g * 8];
  f32x4 s[4];
  #pragma unroll
  for (int kt = 0; kt < 4; kt++)
    s[kt] = __builtin_amdgcn_mfma_f32_16x16x32_bf16(kf[kt], qf, zf, 0, 0, 0);
  int qid = idt[qrow];
  float mx = -1e30f;
  #pragma unroll
  for (int kt = 0; kt < 4; kt++)
    #pragma unroll
    for (int r = 0; r < 4; r++){
      float x = s[kt][r] * scale;
      int idk = (kidp[kt] >> (8 * r)) & 255;
      x += (idk != qid) ? -100.f : 0.f;
      if (kt * 16 + 4 * g + r >= 49) x = -3.0e38f;   // padded key -> exp 0
      s[kt][r] = x;
      mx = fmaxf(mx, x);
    }
  mx = fmaxf(mx, __shfl_xor(mx, 16));
  mx = fmaxf(mx, __shfl_xor(mx, 32));
  float sum = 0.f;
  #pragma unroll
  for (int kt = 0; kt < 4; kt++)
    #pragma unroll
    for (int r = 0; r < 4; r++){
      float e = __expf(s[kt][r] - mx);
      s[kt][r] = e; sum += e;
    }
  sum += __shfl_xor(sum, 16);
  sum += __shfl_xor(sum, 32);
  float inv = 1.f / sum;
  char* plc = (char*)Pl[wid];
  #pragma unroll
  for (int kt = 0; kt < 4; kt++){
    float e0 = s[kt][0] * inv, e1 = s[kt][1] * inv;
    float e2 = s[kt][2] * inv, e3 = s[kt][3] * inv;
    unsigned int pa, pb;
    asm("v_cvt_pk_bf16_f32 %0, %1, %2" : "=v"(pa) : "v"(e0), "v"(e1));
    asm("v_cvt_pk_bf16_f32 %0, %1, %2" : "=v"(pb) : "v"(e2), "v"(e3));
    uint2 w2; w2.x = pa; w2.y = pb;
    *(uint2*)(plc + q15 * 128 + ((kt * 32 + g * 8) ^ ((q15 & 7) << 4))) = w2;
  }
  asm volatile("s_waitcnt lgkmcnt(0)" ::: "memory");
  __builtin_amdgcn_sched_barrier(0);
  f32x4 o[2] = {zf, zf};
  #pragma unroll
  for (int kb = 0; kb < 2; kb++){
    bf16x8 pf = *(const bf16x8*)(plc + q15 * 128 + ((kb * 64 + g * 16) ^ ((q15 & 7) << 4)));
    #pragma unroll
    for (int nt = 0; nt < 2; nt++)
      o[nt] = __builtin_amdgcn_mfma_f32_16x16x32_bf16(pf, vf[kb][nt], o[nt], 0, 0, 0);
  }
  #pragma unroll
  for (int nt = 0; nt < 2; nt++)
    #pragma unroll
    for (int r = 0; r < 4; r++){
      int qp = qt * 16 + 4 * g + r;
      if (qp < 49)
        qkv[base + (size_t)qp * N3C + nt * 16 + q15] = f2bf(o[nt][r]);
    }
}

// ---------------- Depthwise 3x3 conv + bias + tanh-GELU ----------------
#define CONV_T 8
__global__ __launch_bounds__(384)
void conv_gelu_kern(const unsigned short* __restrict__ x1, const unsigned short* __restrict__ wt,
                    const float* __restrict__ kb, unsigned short* __restrict__ out)
{
  int tid = threadIdx.x;
  int c0 = tid * 4;
  h16x4 wv[9];
  #pragma unroll
  for (int j = 0; j < 9; j++) wv[j] = *(const h16x4*)&wt[j * NHID + c0];
  float4 bias = *(const float4*)&kb[c0];

  int n0 = blockIdx.x * CONV_T;
  int rem = n0 % 3136;
  int h = rem / 56, w0 = rem % 56;
  const int hm = (h > 0), hp = (h < 55);
  const unsigned short* base = x1 + (size_t)n0 * NHID + c0;
  const h16x4 z4 = {(_Float16)0, (_Float16)0, (_Float16)0, (_Float16)0};

  h16x4 win[3][3];
  if (w0 > 0){
    win[0][0] = hm ? *(const h16x4*)(base + (-56 - 1) * NHID) : z4;
    win[1][0] =      *(const h16x4*)(base - NHID);
    win[2][0] = hp ? *(const h16x4*)(base + (56 - 1) * NHID) : z4;
  } else { win[0][0] = z4; win[1][0] = z4; win[2][0] = z4; }
  win[0][1] = hm ? *(const h16x4*)(base - 56 * NHID) : z4;
  win[1][1] =      *(const h16x4*)(base);
  win[2][1] = hp ? *(const h16x4*)(base + 56 * NHID) : z4;

  #pragma unroll
  for (int t = 0; t < CONV_T; t++){
    int w = w0 + t;
    const int snew = (t + 2) % 3;
    if (w + 1 <= 55){
      const unsigned short* p = base + (t + 1) * NHID;
      win[0][snew] = hm ? *(const h16x4*)(p - 56 * NHID) : z4;
      win[1][snew] =      *(const h16x4*)(p);
      win[2][snew] = hp ? *(const h16x4*)(p + 56 * NHID) : z4;
    } else { win[0][snew] = z4; win[1][snew] = z4; win[2][snew] = z4; }
    const int s0 = t % 3, s1 = (t + 1) % 3, s2 = snew;
    h16x4 acc = win[0][s0] * wv[0];
    acc += win[0][s1] * wv[1];
    acc += win[0][s2] * wv[2];
    acc += win[1][s0] * wv[3];
    acc += win[1][s1] * wv[4];
    acc += win[1][s2] * wv[5];
    acc += win[2][s0] * wv[6];
    acc += win[2][s1] * wv[7];
    acc += win[2][s2] * wv[8];
    float v0 = (float)acc[0] + bias.x;
    float v1 = (float)acc[1] + bias.y;
    float v2 = (float)acc[2] + bias.z;
    float v3 = (float)acc[3] + bias.w;
    float g0, g1, g2, g3;
    {
      float u, tq, z, e, s;
      u = v0*v0; tq = fmaf(u, 0.07135481627f, 1.5957691216f); z = v0*tq;
      e = __expf(-z); s = __builtin_amdgcn_rcpf(1.f + e); g0 = v0 * s;
      u = v1*v1; tq = fmaf(u, 0.07135481627f, 1.5957691216f); z = v1*tq;
      e = __expf(-z); s = __builtin_amdgcn_rcpf(1.f + e); g1 = v1 * s;
      u = v2*v2; tq = fmaf(u, 0.07135481627f, 1.5957691216f); z = v2*tq;
      e = __expf(-z); s = __builtin_amdgcn_rcpf(1.f + e); g2 = v2 * s;
      u = v3*v3; tq = fmaf(u, 0.07135481627f, 1.5957691216f); z = v3*tq;
      e = __expf(-z); s = __builtin_amdgcn_rcpf(1.f + e); g3 = v3 * s;
    }
    unsigned int pa, pb;
    asm("v_cvt_pk_bf16_f32 %0, %1, %2" : "=v"(pa) : "v"(g0), "v"(g1));
    asm("v_cvt_pk_bf16_f32 %0, %1, %2" : "=v"(pb) : "v"(g2), "v"(g3));
    uint2 w2; w2.x = pa; w2.y = pb;
    *(uint2*)&out[(size_t)(n0 + t) * NHID + c0] = w2;
  }
}

extern "C" void kernel_launch(void* const* d_in, const int* in_sizes, int n_in,
                              void* d_out, int out_size, void* d_ws, size_t ws_size,
                              hipStream_t stream)
{
  const float* x      = (const float*)d_in[0];
  const float* ln1_g  = (const float*)d_in[1];
  const float* ln1_b  = (const float*)d_in[2];
  const float* qkv_w  = (const float*)d_in[3];
  const float* proj_w = (const float*)d_in[4];
  const float* proj_b = (const float*)d_in[5];
  const float* ln2_g  = (const float*)d_in[6];
  const float* ln2_b  = (const float*)d_in[7];
  const float* fc1_w  = (const float*)d_in[8];
  const float* fc1_b  = (const float*)d_in[9];
  const float* dw_k   = (const float*)d_in[10];
  const float* dw_b   = (const float*)d_in[11];
  const float* fc2_w  = (const float*)d_in[12];
  const float* fc2_b  = (const float*)d_in[13];
  float* outp = (float*)d_out;
  char* ws = (char*)d_ws;

  const size_t NEED_BIG   = 215510016;
  const size_t NEED_SPLIT = 90270720;

  if (ws_size >= NEED_BIG){
    unsigned short* xw   = (unsigned short*)(ws);                // 50176*384*2
    unsigned short* qkvh = (unsigned short*)(ws + 38535168);     // 50176*1152*2
    unsigned short* xn2  = (unsigned short*)(ws);                // 25088*384*2
    unsigned short* x1   = (unsigned short*)(ws + 19267584);     // 25088*1536*2 (f16)
    unsigned short* x1g  = (unsigned short*)(ws + 96337920);     // 25088*1536*2 (bf16)
    unsigned short* x2b  = (unsigned short*)(ws + 173408256);    // 50176*384*2 bf16 trunk
    char* wb = ws + 211943424;
    unsigned short* wqkv = (unsigned short*)(wb);
    unsigned short* wproj= (unsigned short*)(wb + 884736);
    unsigned short* wfc1 = (unsigned short*)(wb + 1179648);
    unsigned short* wfc2 = (unsigned short*)(wb + 2359296);
    unsigned short* wdw  = (unsigned short*)(wb + 3538944);

    cvtT_kern<<<dim3(12, 36), 256, 0, stream>>>(qkv_w,  wqkv, 384, 1152);
    cvtT_kern<<<dim3(12, 12), 256, 0, stream>>>(proj_w, wproj, 384, 384);
    cvtT_kern<<<dim3(12, 48), 256, 0, stream>>>(fc1_w,  wfc1, 384, 1536);
    cvtT_kern<<<dim3(48, 12), 256, 0, stream>>>(fc2_w,  wfc2, 1536, 384);
    cvtDW_kern<<<(NHID*9 + 255)/256, 256, 0, stream>>>(dw_k, wdw);

    // attn path, full batch
    ln_kern<<<50176, 64, 0, stream>>>(x, ln1_g, ln1_b, xw, 0, 1);
    gemm_kern<0,256,128,32><<<196*9, 512, 0, stream>>>(xw, 384, wqkv, 384, 1152,
                                                       nullptr, nullptr, qkvh, 0);
    attn_kern<<<12288, 256, 0, stream>>>(qkvh);
    // proj -> bf16 trunk x2b (resid = fp32 x), BN=128
    gemm_kern<6,128,128,64><<<392*3, 256, 0, stream>>>(qkvh, 1152, wproj, 384, 384,
                                                       proj_b, x, x2b, 0);

    // MLP path, two halves; fc2 reads bf16 resid, writes fp32 d_out, BN=128
    for (int hf = 0; hf < 2; hf++){
      int ro = hf * 25088;
      lnb_kern<<<25088, 64, 0, stream>>>(x2b + (size_t)ro * CDIM, ln2_g, ln2_b, xn2);
      gemm_kern<1,256,128,32><<<98*12, 512, 0, stream>>>(xn2, 384, wfc1, 384, 1536,
                                                         fc1_b, nullptr, x1, 0);
      conv_gelu_kern<<<25088 / CONV_T, 384, 0, stream>>>(x1, wdw, dw_b, x1g);
      gemm_kern<5,128,128,64><<<196*3, 256, 0, stream>>>(x1g, 1536, wfc2, 1536, 384,
                                                         fc2_b, (const float*)x2b, outp, ro);
    }
    return;
  }

  if (ws_size < NEED_SPLIT) return;
  // ---------------- fallback: R18 split path (fp32 trunk) ----------------
  unsigned short* xw   = (unsigned short*)(ws);
  unsigned short* qkvh = (unsigned short*)(ws + 19267584);
  unsigned short* xn2q = (unsigned short*)(ws);
  unsigned short* x1q  = (unsigned short*)(ws + 9633792);
  unsigned short* x1gq = (unsigned short*)(ws + 48168960);
  unsigned short* wqkv = (unsigned short*)(ws + 86704128);
  unsigned short* wproj= (unsigned short*)(ws + 87588864);
  unsigned short* wfc1 = (unsigned short*)(ws + 87883776);
  unsigned short* wfc2 = (unsigned short*)(ws + 89063424);
  unsigned short* wdw  = (unsigned short*)(ws + 90243072);

  cvtT_kern<<<dim3(12, 36), 256, 0, stream>>>(qkv_w,  wqkv, 384, 1152);
  cvtT_kern<<<dim3(12, 12), 256, 0, stream>>>(proj_w, wproj, 384, 384);
  cvtT_kern<<<dim3(12, 48), 256, 0, stream>>>(fc1_w,  wfc1, 384, 1536);
  cvtT_kern<<<dim3(48, 12), 256, 0, stream>>>(fc2_w,  wfc2, 1536, 384);
  cvtDW_kern<<<(NHID*9 + 255)/256, 256, 0, stream>>>(dw_k, wdw);

  for (int hf = 0; hf < 2; hf++){
    int ro = hf * 25088;
    ln_kern<<<25088, 64, 0, stream>>>(x, ln1_g, ln1_b, xw, ro, 1);
    gemm_kern<0,256,128,32><<<98*9, 512, 0, stream>>>(xw, 384, wqkv, 384, 1152,
                                                      nullptr, nullptr, qkvh, 0);
    attn_kern<<<6144, 256, 0, stream>>>(qkvh);
    gemm_kern<2,128,64,64><<<196*6, 256, 0, stream>>>(qkvh, 1152, wproj, 384, 384,
                                                      proj_b, x, outp, ro);
  }
  for (int qt = 0; qt < 4; qt++){
    int ro = qt * 12544;
    ln_kern<<<12544, 64, 0, stream>>>(outp + (size_t)ro * CDIM, ln2_g, ln2_b, xn2q, 0, 0);
    gemm_kern<1,256,128,32><<<49*12, 512, 0, stream>>>(xn2q, 384, wfc1, 384, 1536,
                                                       fc1_b, nullptr, x1q, 0);
    conv_gelu_kern<<<12544 / CONV_T, 384, 0, stream>>>(x1q, wdw, dw_b, x1gq);
    gemm_kern<3,128,64,64><<<98*6, 256, 0, stream>>>(x1gq, 1536, wfc2, 1536, 384,
                                                     fc2_b, outp, outp, ro);
  }
}

// Round 23
// 523.482 us; speedup vs baseline: 1.0260x; 1.0260x over previous
//
#include <hip/hip_runtime.h>

// Swin block. fp32 I/O, bf16 internal MFMA operands, bf16 trunk.
// R23: REVERT R22 (BN=128 proj/fc2 lost occupancy: 76->87us). Exact R21 config
//      (best known, 524.3us): proj/fc2 BM=128/BN=64/BK=64, qkv/fc1 BM=256/BK=32,
//      bf16 trunk, XCD remap, R18 two-barrier dbuf K-loop.

using bf16x8 = __attribute__((ext_vector_type(8))) short;
using f32x4  = __attribute__((ext_vector_type(4))) float;
using h16x4  = __attribute__((ext_vector_type(4))) _Float16;

#define CDIM  384
#define N3C   1152
#define NHID  1536

__device__ __forceinline__ float bf2f(unsigned short u){
  union { unsigned int i; float f; } x; x.i = ((unsigned int)u) << 16; return x.f;
}
__device__ __forceinline__ unsigned short f2bf(float f){
  union { float f; unsigned int i; } x; x.f = f;
  unsigned int r = x.i + 0x7fffu + ((x.i >> 16) & 1u);   // RNE
  return (unsigned short)(r >> 16);
}
__device__ __forceinline__ void gload16(const void* g, void* l){
  __builtin_amdgcn_global_load_lds(
      (const __attribute__((address_space(1))) unsigned int*)g,
      (__attribute__((address_space(3))) unsigned int*)l, 16, 0, 0);
}

// ---------------- transpose-convert: wt[n*K+k] = bf16(w[k*N+n]) ----------------
__global__ __launch_bounds__(256)
void cvtT_kern(const float* __restrict__ w, unsigned short* __restrict__ wt, int K, int N){
  __shared__ unsigned short t[32][33];
  int bk = blockIdx.x, bn = blockIdx.y;
  int tr = threadIdx.x >> 5, tc = threadIdx.x & 31;
  #pragma unroll
  for (int r = tr; r < 32; r += 8)
    t[r][tc] = f2bf(w[(size_t)(bk*32 + r) * N + bn*32 + tc]);
  __syncthreads();
  #pragma unroll
  for (int r = tr; r < 32; r += 8)
    wt[(size_t)(bn*32 + r) * K + bk*32 + tc] = t[tc][r];
}

// ---------------- dw weights: [1536][9] fp32 -> [9][1536] f16 ----------------
__global__ __launch_bounds__(256)
void cvtDW_kern(const float* __restrict__ k, unsigned short* __restrict__ wt){
  int i = blockIdx.x * 256 + threadIdx.x;
  if (i < NHID * 9){
    int c = i / 9, tap = i % 9;
    union { _Float16 h; unsigned short u; } cvt; cvt.h = (_Float16)k[i];
    wt[tap * NHID + c] = cvt.u;
  }
}

// ---------------- LayerNorm fp32-in (+optional roll+window gather), bf16 out ----------
__global__ __launch_bounds__(64)
void ln_kern(const float* __restrict__ xin, const float* __restrict__ g,
             const float* __restrict__ bsh, unsigned short* __restrict__ out,
             int row_off, int do_shift)
{
  int blk = blockIdx.x, t = threadIdx.x;
  size_t src;
  if (do_shift){
    int gl = row_off + blk;
    int bb = gl / 3136, rem = gl % 3136;
    int wi = rem / 49, l = rem % 49;
    int h = (wi >> 3) * 7 + l / 7;
    int w = (wi & 7) * 7 + l % 7;
    int sh = h + 3; if (sh >= 56) sh -= 56;    // roll(-3)
    int sw = w + 3; if (sw >= 56) sw -= 56;
    src = ((size_t)bb * 3136 + sh * 56 + sw) * CDIM;
  } else {
    src = (size_t)blk * CDIM;
  }
  float v[6]; float s = 0.f;
  #pragma unroll
  for (int j = 0; j < 6; j++){ v[j] = xin[src + j*64 + t]; s += v[j]; }
  #pragma unroll
  for (int m = 32; m >= 1; m >>= 1) s += __shfl_xor(s, m);
  float mean = s * (1.f/384.f);
  float q = 0.f;
  #pragma unroll
  for (int j = 0; j < 6; j++){ float d = v[j] - mean; q += d * d; }
  #pragma unroll
  for (int m = 32; m >= 1; m >>= 1) q += __shfl_xor(q, m);
  float rstd = rsqrtf(q * (1.f/384.f) + 1e-5f);
  size_t dst = (size_t)blk * CDIM;
  #pragma unroll
  for (int j = 0; j < 6; j++){
    int c = j*64 + t;
    out[dst + c] = f2bf((v[j] - mean) * rstd * g[c] + bsh[c]);
  }
}

// ---------------- LayerNorm bf16-in (linear), bf16 out ----------
__global__ __launch_bounds__(64)
void lnb_kern(const unsigned short* __restrict__ xin, const float* __restrict__ g,
              const float* __restrict__ bsh, unsigned short* __restrict__ out)
{
  int blk = blockIdx.x, t = threadIdx.x;
  size_t src = (size_t)blk * CDIM;
  float v[6]; float s = 0.f;
  #pragma unroll
  for (int j = 0; j < 6; j++){ v[j] = bf2f(xin[src + j*64 + t]); s += v[j]; }
  #pragma unroll
  for (int m = 32; m >= 1; m >>= 1) s += __shfl_xor(s, m);
  float mean = s * (1.f/384.f);
  float q = 0.f;
  #pragma unroll
  for (int j = 0; j < 6; j++){ float d = v[j] - mean; q += d * d; }
  #pragma unroll
  for (int m = 32; m >= 1; m >>= 1) q += __shfl_xor(q, m);
  float rstd = rsqrtf(q * (1.f/384.f) + 1e-5f);
  #pragma unroll
  for (int j = 0; j < 6; j++){
    int c = j*64 + t;
    out[src + c] = f2bf((v[j] - mean) * rstd * g[c] + bsh[c]);
  }
}

// ---------------- MFMA GEMM, 2-phase dbuf (R18 form), XCD-chunked 1-D grid ----------------
// MODE 0: plain bf16 out (qkv). 1: +bias, f16 out (fc1). 2: proj->fp32 trunk (split path).
// 3: fc2 fp32-resid (split path). 5: fc2 bf16-resid -> fp32 out. 6: proj -> bf16 x2b.
template<int MODE, int BM, int BN, int BK>
__global__ __launch_bounds__(BM*2)
void gemm_kern(const unsigned short* __restrict__ A, int lda,
               const unsigned short* __restrict__ Bt, int K, int N,
               const float* __restrict__ bias, const float* __restrict__ resid,
               void* __restrict__ outv, int row_off)
{
  constexpr int NI = BN / 32;
  constexpr int T  = BM * 2;
  constexpr int SUBK = BK / 32;
  __shared__ __align__(16) unsigned short Al[2][SUBK * BM * 32];
  __shared__ __align__(16) unsigned short Bl[2][SUBK * BN * 32];
  int tid = threadIdx.x;
  int lane = tid & 63, wv = tid >> 6;

  // bijective XCD chunk remap (m204)
  int nwg = gridDim.x, bid = blockIdx.x;
  int q8 = nwg >> 3, r8 = nwg & 7;
  int xcd = bid & 7, idx = bid >> 3;
  int l = ((xcd < r8) ? xcd * (q8 + 1) : r8 * (q8 + 1) + (xcd - r8) * q8) + idx;
  const int NT = N / BN;
  int m0 = (l / NT) * BM, n0 = (l % NT) * BN;

  const int wrow = (wv >> 1) * 64;
  const int wcol = (wv & 1) * (BN / 2);
  const int lr = lane & 15, lk = (lane >> 4) * 8;

  auto STAGE = [&](int buf, int k0){
    #pragma unroll
    for (int s = 0; s < SUBK; s++){
      #pragma unroll
      for (int i = 0; i < 2; i++){
        int c = i*T + tid;
        gload16(&A[(size_t)(m0 + (c >> 2)) * lda + k0 + s*32 + (c & 3) * 8],
                &Al[buf][s*BM*32 + (i*T + wv*64) * 8]);
      }
      {
        int c = tid;
        gload16(&Bt[(size_t)(n0 + (c >> 2)) * K + k0 + s*32 + (c & 3) * 8],
                &Bl[buf][s*BN*32 + (wv*64) * 8]);
      }
    }
  };

  f32x4 acc[4][NI] = {};
  const int nt = K / BK;
  STAGE(0, 0);
  for (int t = 0; t < nt; ++t){
    int cur = t & 1;
    if (t + 1 < nt){
      STAGE(cur ^ 1, (t + 1) * BK);
      if constexpr (SUBK == 1) asm volatile("s_waitcnt vmcnt(3)" ::: "memory");
      else                     asm volatile("s_waitcnt vmcnt(6)" ::: "memory");
    } else {
      asm volatile("s_waitcnt vmcnt(0)" ::: "memory");
    }
    __builtin_amdgcn_s_barrier();
    __builtin_amdgcn_sched_barrier(0);
    #pragma unroll
    for (int kk = 0; kk < SUBK; kk++){
      bf16x8 af[4], bfr[NI];
      #pragma unroll
      for (int mi = 0; mi < 4; mi++)
        af[mi] = *(const bf16x8*)&Al[cur][kk*BM*32 + (wrow + mi*16 + lr)*32 + lk];
      #pragma unroll
      for (int ni = 0; ni < NI; ni++)
        bfr[ni] = *(const bf16x8*)&Bl[cur][kk*BN*32 + (wcol + ni*16 + lr)*32 + lk];
      #pragma unroll
      for (int mi = 0; mi < 4; mi++)
        #pragma unroll
        for (int ni = 0; ni < NI; ni++)
          acc[mi][ni] = __builtin_amdgcn_mfma_f32_16x16x32_bf16(af[mi], bfr[ni], acc[mi][ni], 0, 0, 0);
    }
    __builtin_amdgcn_sched_barrier(0);
    __builtin_amdgcn_s_barrier();
    __builtin_amdgcn_sched_barrier(0);
  }

  #pragma unroll
  for (int mi = 0; mi < 4; mi++)
  #pragma unroll
  for (int ni = 0; ni < NI; ni++)
  #pragma unroll
  for (int j = 0; j < 4; j++){
    int row = m0 + wrow + mi*16 + (lane >> 4) * 4 + j;   // C/D layout (m89/m91)
    int col = n0 + wcol + ni*16 + lr;
    float val = acc[mi][ni][j];
    if (MODE == 0){
      ((unsigned short*)outv)[(size_t)row * N + col] = f2bf(val);
    } else if (MODE == 1){
      union { _Float16 h; unsigned short u; } cvt;
      cvt.h = (_Float16)(val + bias[col]);
      ((unsigned short*)outv)[(size_t)row * N + col] = cvt.u;
    } else if (MODE == 2 || MODE == 6){
      val += bias[col];
      int gl = row_off + row;
      int bb = gl / 3136, rem = gl % 3136;
      int wi = rem / 49, l2 = rem % 49;
      int n = ((wi >> 3) * 7 + l2 / 7) * 56 + (wi & 7) * 7 + l2 % 7;  // window reverse
      size_t idx2 = ((size_t)bb * 3136 + n) * CDIM + col;
      if (MODE == 2) ((float*)outv)[idx2] = resid[idx2] + val;
      else           ((unsigned short*)outv)[idx2] = f2bf(resid[idx2] + val);
    } else if (MODE == 5){
      size_t idx2 = (size_t)(row_off + row) * CDIM + col;
      float r = bf2f(((const unsigned short*)resid)[idx2]);
      ((float*)outv)[idx2] = r + val + bias[col];
    } else {
      size_t idx2 = (size_t)(row_off + row) * CDIM + col;
      ((float*)outv)[idx2] = resid[idx2] + val + bias[col];
    }
  }
}

// ---------------- Windowed attention: 4 waves per (window, head), one q-tile per wave ------
__global__ __launch_bounds__(256)
void attn_kern(unsigned short* __restrict__ qkv)
{
  __shared__ __align__(16) unsigned short Vt[32 * 64];
  __shared__ __align__(16) unsigned short Pl[4][16 * 64];
  __shared__ unsigned char idt[49];
  int blk = blockIdx.x;
  int win = blk / 12, head = blk % 12;
  int tid = threadIdx.x;
  int wid = tid >> 6, l = tid & 63;
  int g = l >> 4, q15 = l & 15;
  size_t base = (size_t)win * 49 * N3C + (size_t)head * 32;
  const unsigned short* kp = qkv + base + 384;
  const unsigned short* vp = qkv + base + 768;

  int wi = win & 63;
  if (wid == 0 && l < 49){
    int h = (wi >> 3) * 7 + l / 7;
    int w = (wi & 7) * 7 + l % 7;
    idt[l] = (unsigned char)((h < 49 ? 0 : (h < 53 ? 1 : 2)) * 3 +
                             (w < 49 ? 0 : (w < 53 ? 1 : 2)));
  }
  {
    int c = tid;
    int key = c >> 2, keyc = min(key, 48), d0 = (c & 3) * 8;
    bf16x8 v = *(const bf16x8*)&vp[(size_t)keyc * N3C + d0];
    #pragma unroll
    for (int j = 0; j < 8; j++){
      int d = d0 + j;
      *(unsigned short*)((char*)Vt + d * 128 + ((key * 2) ^ ((d & 7) << 4))) =
          (unsigned short)v[j];
    }
  }
  __syncthreads();

  bf16x8 kf[4];
  #pragma unroll
  for (int kt = 0; kt < 4; kt++){
    int krow = min(kt * 16 + q15, 48);
    kf[kt] = *(const bf16x8*)&kp[(size_t)krow * N3C + g * 8];
  }
  bf16x8 vf[2][2];
  #pragma unroll
  for (int kb = 0; kb < 2; kb++)
    #pragma unroll
    for (int nt = 0; nt < 2; nt++){
      int n = nt * 16 + q15;
      vf[kb][nt] = *(const bf16x8*)((char*)Vt + n * 128 + ((kb * 64 + g * 16) ^ ((n & 7) << 4)));
    }
  unsigned int kidp[4];
  #pragma unroll
  for (int kt = 0; kt < 4; kt++){
    unsigned int p = 0;
    #pragma unroll
    for (int r = 0; r < 4; r++)
      p |= ((unsigned int)idt[min(kt * 16 + 4 * g + r, 48)]) << (8 * r);
    kidp[kt] = p;
  }

  const float scale = 0.17677669529663687f;
  const f32x4 zf = {0.f, 0.f, 0.f, 0.f};
  const int qt = wid;
  int qrow = min(qt * 16 + q15, 48);
  bf16x8 qf = *(const bf16x8*)&qkv[base + (size_t)qrow * N3C + g * 8];
  f32x4 s[4];
  #pragma unroll
  for (int kt = 0; kt < 4; kt++)
    s[kt] = __builtin_amdgcn_mfma_f32_16x16x32_bf16(kf[kt], qf, zf, 0, 0, 0);
  int qid = idt[qrow];
  float mx = -1e30f;
  #pragma unroll
  for (int kt = 0; kt < 4; kt++)
    #pragma unroll
    for (int r = 0; r < 4; r++){
      float x = s[kt][r] * scale;
      int idk = (kidp[kt] >> (8 * r)) & 255;
      x += (idk != qid) ? -100.f : 0.f;
      if (kt * 16 + 4 * g + r >= 49) x = -3.0e38f;   // padded key -> exp 0
      s[kt][r] = x;
      mx = fmaxf(mx, x);
    }
  mx = fmaxf(mx, __shfl_xor(mx, 16));
  mx = fmaxf(mx, __shfl_xor(mx, 32));
  float sum = 0.f;
  #pragma unroll
  for (int kt = 0; kt < 4; kt++)
    #pragma unroll
    for (int r = 0; r < 4; r++){
      float e = __expf(s[kt][r] - mx);
      s[kt][r] = e; sum += e;
    }
  sum += __shfl_xor(sum, 16);
  sum += __shfl_xor(sum, 32);
  float inv = 1.f / sum;
  char* plc = (char*)Pl[wid];
  #pragma unroll
  for (int kt = 0; kt < 4; kt++){
    float e0 = s[kt][0] * inv, e1 = s[kt][1] * inv;
    float e2 = s[kt][2] * inv, e3 = s[kt][3] * inv;
    unsigned int pa, pb;
    asm("v_cvt_pk_bf16_f32 %0, %1, %2" : "=v"(pa) : "v"(e0), "v"(e1));
    asm("v_cvt_pk_bf16_f32 %0, %1, %2" : "=v"(pb) : "v"(e2), "v"(e3));
    uint2 w2; w2.x = pa; w2.y = pb;
    *(uint2*)(plc + q15 * 128 + ((kt * 32 + g * 8) ^ ((q15 & 7) << 4))) = w2;
  }
  asm volatile("s_waitcnt lgkmcnt(0)" ::: "memory");
  __builtin_amdgcn_sched_barrier(0);
  f32x4 o[2] = {zf, zf};
  #pragma unroll
  for (int kb = 0; kb < 2; kb++){
    bf16x8 pf = *(const bf16x8*)(plc + q15 * 128 + ((kb * 64 + g * 16) ^ ((q15 & 7) << 4)));
    #pragma unroll
    for (int nt = 0; nt < 2; nt++)
      o[nt] = __builtin_amdgcn_mfma_f32_16x16x32_bf16(pf, vf[kb][nt], o[nt], 0, 0, 0);
  }
  #pragma unroll
  for (int nt = 0; nt < 2; nt++)
    #pragma unroll
    for (int r = 0; r < 4; r++){
      int qp = qt * 16 + 4 * g + r;
      if (qp < 49)
        qkv[base + (size_t)qp * N3C + nt * 16 + q15] = f2bf(o[nt][r]);
    }
}

// ---------------- Depthwise 3x3 conv + bias + tanh-GELU ----------------
#define CONV_T 8
__global__ __launch_bounds__(384)
void conv_gelu_kern(const unsigned short* __restrict__ x1, const unsigned short* __restrict__ wt,
                    const float* __restrict__ kb, unsigned short* __restrict__ out)
{
  int tid = threadIdx.x;
  int c0 = tid * 4;
  h16x4 wv[9];
  #pragma unroll
  for (int j = 0; j < 9; j++) wv[j] = *(const h16x4*)&wt[j * NHID + c0];
  float4 bias = *(const float4*)&kb[c0];

  int n0 = blockIdx.x * CONV_T;
  int rem = n0 % 3136;
  int h = rem / 56, w0 = rem % 56;
  const int hm = (h > 0), hp = (h < 55);
  const unsigned short* base = x1 + (size_t)n0 * NHID + c0;
  const h16x4 z4 = {(_Float16)0, (_Float16)0, (_Float16)0, (_Float16)0};

  h16x4 win[3][3];
  if (w0 > 0){
    win[0][0] = hm ? *(const h16x4*)(base + (-56 - 1) * NHID) : z4;
    win[1][0] =      *(const h16x4*)(base - NHID);
    win[2][0] = hp ? *(const h16x4*)(base + (56 - 1) * NHID) : z4;
  } else { win[0][0] = z4; win[1][0] = z4; win[2][0] = z4; }
  win[0][1] = hm ? *(const h16x4*)(base - 56 * NHID) : z4;
  win[1][1] =      *(const h16x4*)(base);
  win[2][1] = hp ? *(const h16x4*)(base + 56 * NHID) : z4;

  #pragma unroll
  for (int t = 0; t < CONV_T; t++){
    int w = w0 + t;
    const int snew = (t + 2) % 3;
    if (w + 1 <= 55){
      const unsigned short* p = base + (t + 1) * NHID;
      win[0][snew] = hm ? *(const h16x4*)(p - 56 * NHID) : z4;
      win[1][snew] =      *(const h16x4*)(p);
      win[2][snew] = hp ? *(const h16x4*)(p + 56 * NHID) : z4;
    } else { win[0][snew] = z4; win[1][snew] = z4; win[2][snew] = z4; }
    const int s0 = t % 3, s1 = (t + 1) % 3, s2 = snew;
    h16x4 acc = win[0][s0] * wv[0];
    acc += win[0][s1] * wv[1];
    acc += win[0][s2] * wv[2];
    acc += win[1][s0] * wv[3];
    acc += win[1][s1] * wv[4];
    acc += win[1][s2] * wv[5];
    acc += win[2][s0] * wv[6];
    acc += win[2][s1] * wv[7];
    acc += win[2][s2] * wv[8];
    float v0 = (float)acc[0] + bias.x;
    float v1 = (float)acc[1] + bias.y;
    float v2 = (float)acc[2] + bias.z;
    float v3 = (float)acc[3] + bias.w;
    float g0, g1, g2, g3;
    {
      float u, tq, z, e, s;
      u = v0*v0; tq = fmaf(u, 0.07135481627f, 1.5957691216f); z = v0*tq;
      e = __expf(-z); s = __builtin_amdgcn_rcpf(1.f + e); g0 = v0 * s;
      u = v1*v1; tq = fmaf(u, 0.07135481627f, 1.5957691216f); z = v1*tq;
      e = __expf(-z); s = __builtin_amdgcn_rcpf(1.f + e); g1 = v1 * s;
      u = v2*v2; tq = fmaf(u, 0.07135481627f, 1.5957691216f); z = v2*tq;
      e = __expf(-z); s = __builtin_amdgcn_rcpf(1.f + e); g2 = v2 * s;
      u = v3*v3; tq = fmaf(u, 0.07135481627f, 1.5957691216f); z = v3*tq;
      e = __expf(-z); s = __builtin_amdgcn_rcpf(1.f + e); g3 = v3 * s;
    }
    unsigned int pa, pb;
    asm("v_cvt_pk_bf16_f32 %0, %1, %2" : "=v"(pa) : "v"(g0), "v"(g1));
    asm("v_cvt_pk_bf16_f32 %0, %1, %2" : "=v"(pb) : "v"(g2), "v"(g3));
    uint2 w2; w2.x = pa; w2.y = pb;
    *(uint2*)&out[(size_t)(n0 + t) * NHID + c0] = w2;
  }
}

extern "C" void kernel_launch(void* const* d_in, const int* in_sizes, int n_in,
                              void* d_out, int out_size, void* d_ws, size_t ws_size,
                              hipStream_t stream)
{
  const float* x      = (const float*)d_in[0];
  const float* ln1_g  = (const float*)d_in[1];
  const float* ln1_b  = (const float*)d_in[2];
  const float* qkv_w  = (const float*)d_in[3];
  const float* proj_w = (const float*)d_in[4];
  const float* proj_b = (const float*)d_in[5];
  const float* ln2_g  = (const float*)d_in[6];
  const float* ln2_b  = (const float*)d_in[7];
  const float* fc1_w  = (const float*)d_in[8];
  const float* fc1_b  = (const float*)d_in[9];
  const float* dw_k   = (const float*)d_in[10];
  const float* dw_b   = (const float*)d_in[11];
  const float* fc2_w  = (const float*)d_in[12];
  const float* fc2_b  = (const float*)d_in[13];
  float* outp = (float*)d_out;
  char* ws = (char*)d_ws;

  const size_t NEED_BIG   = 215510016;   // 173.4M era + 38.5M x2b + 3.57M weights
  const size_t NEED_SPLIT = 90270720;

  if (ws_size >= NEED_BIG){
    unsigned short* xw   = (unsigned short*)(ws);                // 50176*384*2
    unsigned short* qkvh = (unsigned short*)(ws + 38535168);     // 50176*1152*2
    unsigned short* xn2  = (unsigned short*)(ws);                // 25088*384*2
    unsigned short* x1   = (unsigned short*)(ws + 19267584);     // 25088*1536*2 (f16)
    unsigned short* x1g  = (unsigned short*)(ws + 96337920);     // 25088*1536*2 (bf16)
    unsigned short* x2b  = (unsigned short*)(ws + 173408256);    // 50176*384*2 bf16 trunk
    char* wb = ws + 211943424;
    unsigned short* wqkv = (unsigned short*)(wb);
    unsigned short* wproj= (unsigned short*)(wb + 884736);
    unsigned short* wfc1 = (unsigned short*)(wb + 1179648);
    unsigned short* wfc2 = (unsigned short*)(wb + 2359296);
    unsigned short* wdw  = (unsigned short*)(wb + 3538944);

    cvtT_kern<<<dim3(12, 36), 256, 0, stream>>>(qkv_w,  wqkv, 384, 1152);
    cvtT_kern<<<dim3(12, 12), 256, 0, stream>>>(proj_w, wproj, 384, 384);
    cvtT_kern<<<dim3(12, 48), 256, 0, stream>>>(fc1_w,  wfc1, 384, 1536);
    cvtT_kern<<<dim3(48, 12), 256, 0, stream>>>(fc2_w,  wfc2, 1536, 384);
    cvtDW_kern<<<(NHID*9 + 255)/256, 256, 0, stream>>>(dw_k, wdw);

    // attn path, full batch
    ln_kern<<<50176, 64, 0, stream>>>(x, ln1_g, ln1_b, xw, 0, 1);
    gemm_kern<0,256,128,32><<<196*9, 512, 0, stream>>>(xw, 384, wqkv, 384, 1152,
                                                       nullptr, nullptr, qkvh, 0);
    attn_kern<<<12288, 256, 0, stream>>>(qkvh);
    // proj -> bf16 trunk x2b (resid = fp32 x)
    gemm_kern<6,128,64,64><<<392*6, 256, 0, stream>>>(qkvh, 1152, wproj, 384, 384,
                                                      proj_b, x, x2b, 0);

    // MLP path, two halves; fc2 reads bf16 resid, writes fp32 d_out
    for (int hf = 0; hf < 2; hf++){
      int ro = hf * 25088;
      lnb_kern<<<25088, 64, 0, stream>>>(x2b + (size_t)ro * CDIM, ln2_g, ln2_b, xn2);
      gemm_kern<1,256,128,32><<<98*12, 512, 0, stream>>>(xn2, 384, wfc1, 384, 1536,
                                                         fc1_b, nullptr, x1, 0);
      conv_gelu_kern<<<25088 / CONV_T, 384, 0, stream>>>(x1, wdw, dw_b, x1g);
      gemm_kern<5,128,64,64><<<196*6, 256, 0, stream>>>(x1g, 1536, wfc2, 1536, 384,
                                                        fc2_b, (const float*)x2b, outp, ro);
    }
    return;
  }

  if (ws_size < NEED_SPLIT) return;
  // ---------------- fallback: R18 split path (fp32 trunk) ----------------
  unsigned short* xw   = (unsigned short*)(ws);
  unsigned short* qkvh = (unsigned short*)(ws + 19267584);
  unsigned short* xn2q = (unsigned short*)(ws);
  unsigned short* x1q  = (unsigned short*)(ws + 9633792);
  unsigned short* x1gq = (unsigned short*)(ws + 48168960);
  unsigned short* wqkv = (unsigned short*)(ws + 86704128);
  unsigned short* wproj= (unsigned short*)(ws + 87588864);
  unsigned short* wfc1 = (unsigned short*)(ws + 87883776);
  unsigned short* wfc2 = (unsigned short*)(ws + 89063424);
  unsigned short* wdw  = (unsigned short*)(ws + 90243072);

  cvtT_kern<<<dim3(12, 36), 256, 0, stream>>>(qkv_w,  wqkv, 384, 1152);
  cvtT_kern<<<dim3(12, 12), 256, 0, stream>>>(proj_w, wproj, 384, 384);
  cvtT_kern<<<dim3(12, 48), 256, 0, stream>>>(fc1_w,  wfc1, 384, 1536);
  cvtT_kern<<<dim3(48, 12), 256, 0, stream>>>(fc2_w,  wfc2, 1536, 384);
  cvtDW_kern<<<(NHID*9 + 255)/256, 256, 0, stream>>>(dw_k, wdw);

  for (int hf = 0; hf < 2; hf++){
    int ro = hf * 25088;
    ln_kern<<<25088, 64, 0, stream>>>(x, ln1_g, ln1_b, xw, ro, 1);
    gemm_kern<0,256,128,32><<<98*9, 512, 0, stream>>>(xw, 384, wqkv, 384, 1152,
                                                      nullptr, nullptr, qkvh, 0);
    attn_kern<<<6144, 256, 0, stream>>>(qkvh);
    gemm_kern<2,128,64,64><<<196*6, 256, 0, stream>>>(qkvh, 1152, wproj, 384, 384,
                                                      proj_b, x, outp, ro);
  }
  for (int qt = 0; qt < 4; qt++){
    int ro = qt * 12544;
    ln_kern<<<12544, 64, 0, stream>>>(outp + (size_t)ro * CDIM, ln2_g, ln2_b, xn2q, 0, 0);
    gemm_kern<1,256,128,32><<<49*12, 512, 0, stream>>>(xn2q, 384, wfc1, 384, 1536,
                                                       fc1_b, nullptr, x1q, 0);
    conv_gelu_kern<<<12544 / CONV_T, 384, 0, stream>>>(x1q, wdw, dw_b, x1gq);
    gemm_kern<3,128,64,64><<<98*6, 256, 0, stream>>>(x1gq, 1536, wfc2, 1536, 384,
                                                     fc2_b, outp, outp, ro);
  }
}